// Round 6
// baseline (126.584 us; speedup 1.0000x reference)
//
#include <hip/hip_runtime.h>
#include <cmath>

// CapsuleLayer routing, B=64, Ni=2048, Di=16, No=32, Do=16 (fp32 in/out).
// R10 = R9 (best: 124.97us total; fused ~39us, reduce ~6.5us, ~80us fixed
// harness poison-fills) + three additive changes:
//  (1) x preloaded for the whole 8-n group in the prologue (16KB LDS,
//      read-only in loop) -> per-iter x staging/prefetch/branch deleted.
//  (2) s_setprio(1) around the MFMA+h phase: 2 blocks/CU run at independent
//      phases (attn-like regime where setprio measured +4-7%, m191).
//  (3) reduce kernel regridded: 2048 blocks x 256 thr, 16 loads/thread,
//      32 waves/CU (was 512 blocks, 256 loads/thread) -> latency-hiding.
// Kept from R9 (all verified): 2-way b-split (4096 block-n-iters), XOR-swizzled
// pad-free LDS (conflicts 0), cvt_pk bf16 split staging, 2-barrier single-buffer
// pipeline with W prefetch, (512,4) bounds (only proven spill-free cap),
// XCD-paired blockIdx swizzle, gidx-major partial epilogue.

#define NI 2048
#define NGROUPS 256
#define NPER 8

typedef short bf16x8 __attribute__((ext_vector_type(8)));
typedef float f32x4 __attribute__((ext_vector_type(4)));

static __device__ __forceinline__ unsigned cvt_pk_bf16(float a, float b) {
  unsigned r;
  asm("v_cvt_pk_bf16_f32 %0, %1, %2" : "=v"(r) : "v"(a), "v"(b));
  return r;  // lo16 = bf16(a), hi16 = bf16(b), RNE
}
// fp32 -> (hi bf16x4, lo bf16x4) with hi+lo ~ full precision
static __device__ __forceinline__ void split4_pk(float4 v, uint2& hi, uint2& lo) {
  hi.x = cvt_pk_bf16(v.x, v.y);
  hi.y = cvt_pk_bf16(v.z, v.w);
  float r0 = v.x - __uint_as_float(hi.x << 16);
  float r1 = v.y - __uint_as_float(hi.x & 0xFFFF0000u);
  float r2 = v.z - __uint_as_float(hi.y << 16);
  float r3 = v.w - __uint_as_float(hi.y & 0xFFFF0000u);
  lo.x = cvt_pk_bf16(r0, r1);
  lo.y = cvt_pk_bf16(r2, r3);
}
// dword offset of 16B unit u (0/1) of row r in a rows-of-8-dwords array,
// XOR-swizzled so stride-8 row reads spread across banks (both sides use it).
static __device__ __forceinline__ int swz8(int r, int u) {
  return r * 8 + ((u ^ ((r >> 2) & 1)) << 2);
}

// ---------------- Fused kernel: MFMA + in-block routing + weighted accumulate ----
// grid 512; xcd = bx&7, slot = bx>>3 (0..63); ng = xcd*32 + (slot>>1); bh = slot&1
// (both bh blocks of an ng on one XCD -> W read once per XCD from L2/L3).
// block 512 = 8 waves = (bt = wv&1: 16-b tile of the 32-b half) x (oq = wv>>1:
// o-octet). Wave: o = oq*8 .. oq*8+7, b = bt*16 .. +15.
// A = [W_hi|W_lo] (m=d, K=32 packed split), B = [x_hi],[x_lo] dup along K.
// LDS dword offsets (rows of 8 dwords, swizzled):
#define WAOFF 0        // 32 o * 32 rows (s*16+d) * 8 = 8192
#define XLOFF 8192     // 8 n * 64 rows (s*32 + b_local) * 8 = 4096 (read-only in loop)
#define HOFF  12288    // h[b_local][o]: 32 * 33 = 1056
#define C2OFF 13344    // c2[o][b_local]: 32 * 33 = 1056
#define LDSZ  14400    // 57.6 KB -> 2 blocks/CU
__global__ __launch_bounds__(512, 4) void caps_fused_kernel(
    const float* __restrict__ x, const float* __restrict__ W,
    float* __restrict__ partial)
{
  const int bx = blockIdx.x;
  const int xcd = bx & 7, slot = bx >> 3;
  const int ng = xcd * 32 + (slot >> 1);
  const int bh = slot & 1;
  const int t = threadIdx.x;
  const int wv = t >> 6, l = t & 63;
  const int q = l >> 4, dq = l & 15, qh = q & 1, s_a = q >> 1;
  const int bt = wv & 1, oq = wv >> 1;

  __shared__ __align__(16) float lds[LDSZ];
  float* WA  = lds + WAOFF;
  float* XL  = lds + XLOFF;
  float* hS  = lds + HOFF;
  float* c2S = lds + C2OFF;

  float sacc[8][4];
  #pragma unroll
  for (int oo = 0; oo < 8; ++oo)
    { sacc[oo][0] = 0.f; sacc[oo][1] = 0.f; sacc[oo][2] = 0.f; sacc[oo][3] = 0.f; }

  const int n0 = ng * NPER;
  // W staging decomposition: chunk c covers o = c*8 + wv; (d, i4) from t
  const int wd = (t >> 2) & 15, wi4 = t & 3;
  const int wu = wi4 >> 1, wsub = (wi4 & 1) * 2;

  // ---- prologue: stage W(n0) + ALL x for the group; then prefetch W(n0+1) ----
  float4 wreg[4];
  #pragma unroll
  for (int c = 0; c < 4; ++c)
    wreg[c] = *(const float4*)(W + (size_t)n0 * 8192 + c * 2048 + 4 * t);

  // x preload: 1024 float4 segments (b 0..31, n 0..7, i4 0..3), 2 per thread
  #pragma unroll
  for (int m = 0; m < 2; ++m) {
    const int idx = m * 512 + t;
    const int pb = idx >> 5, pn = (idx >> 2) & 7, pi4 = idx & 3;
    float4 v = *(const float4*)(x + (size_t)(bh * 32 + pb) * (NI * 16)
                                 + (n0 + pn) * 16 + pi4 * 4);
    uint2 hi, lo;
    split4_pk(v, hi, lo);
    const int pu = pi4 >> 1, psub = (pi4 & 1) * 2;
    float* XLn = XL + pn * 512;
    *(uint2*)&XLn[swz8(pb, pu) + psub] = hi;
    *(uint2*)&XLn[swz8(32 + pb, pu) + psub] = lo;
  }

  #pragma unroll
  for (int c = 0; c < 4; ++c) {
    uint2 hi, lo;
    split4_pk(wreg[c], hi, lo);
    const int rh = (c * 8 + wv) * 32 + wd;
    *(uint2*)&WA[swz8(rh, wu) + wsub] = hi;
    *(uint2*)&WA[swz8(rh + 16, wu) + wsub] = lo;
  }
  __syncthreads();

  {
    const size_t nb = (size_t)(n0 + 1);
    #pragma unroll
    for (int c = 0; c < 4; ++c)
      wreg[c] = *(const float4*)(W + nb * 8192 + c * 2048 + 4 * t);
  }

  #pragma unroll 1
  for (int nn = 0; nn < NPER; ++nn) {
    // ---- phase 1: MFMA from LDS (data nn); h = row-sum(D) -> hS ----
    f32x4 Dv[8];
    {
      const float* XLn = XL + nn * 512;
      __builtin_amdgcn_s_setprio(1);
      bf16x8 B0 = *(const bf16x8*)&XLn[swz8(bt * 16 + dq, qh)];        // x_hi
      bf16x8 B1 = *(const bf16x8*)&XLn[swz8(32 + bt * 16 + dq, qh)];   // x_lo
      #pragma unroll
      for (int oo = 0; oo < 8; ++oo) {
        const int o = oq * 8 + oo;
        bf16x8 A = *(const bf16x8*)&WA[swz8(o * 32 + s_a * 16 + dq, qh)];
        f32x4 D = {0.f, 0.f, 0.f, 0.f};
        D = __builtin_amdgcn_mfma_f32_16x16x32_bf16(A, B0, D, 0, 0, 0);
        D = __builtin_amdgcn_mfma_f32_16x16x32_bf16(A, B1, D, 0, 0, 0);
        Dv[oo] = D;
        float hs = D[0] + D[1] + D[2] + D[3];   // sum over d within q-group
        hs += __shfl_xor(hs, 16);
        hs += __shfl_xor(hs, 32);               // sum over q
        if (q == 0) hS[(bt * 16 + dq) * 33 + o] = hs;
      }
      __builtin_amdgcn_s_setprio(0);
    }
    __syncthreads();   // syncA: hS ready; MFMA reads of WA(nn) complete

    // ---- phase 2a: stage W data nn+1 into WA (pipelined, single buffer) ----
    if (nn < NPER - 1) {
      #pragma unroll
      for (int c = 0; c < 4; ++c) {
        uint2 hi, lo;
        split4_pk(wreg[c], hi, lo);
        const int rh = (c * 8 + wv) * 32 + wd;
        *(uint2*)&WA[swz8(rh, wu) + wsub] = hi;
        *(uint2*)&WA[swz8(rh + 16, wu) + wsub] = lo;
      }
    }

    // ---- phase 2b: routing (R5-proven): thread (bl = t>>4, op = t&15)
    //      handles o = op and op+16; softmax reduce via 16-lane shuffles ----
    {
      const int bl = t >> 4, op = t & 15;
      const float h0 = hS[bl * 33 + op];
      const float h1 = hS[bl * 33 + op + 16];
      const float b10 = h0 * 0.03125f, b11 = h1 * 0.03125f;
      float mx = fmaxf(b10, b11);
      mx = fmaxf(mx, __shfl_xor(mx, 1)); mx = fmaxf(mx, __shfl_xor(mx, 2));
      mx = fmaxf(mx, __shfl_xor(mx, 4)); mx = fmaxf(mx, __shfl_xor(mx, 8));
      const float e0 = __expf(b10 - mx), e1 = __expf(b11 - mx);
      float S = e0 + e1;
      S += __shfl_xor(S, 1); S += __shfl_xor(S, 2);
      S += __shfl_xor(S, 4); S += __shfl_xor(S, 8);
      const float inv = 1.0f / S;
      const float b20 = b10 + e0 * inv * h0, b21 = b11 + e1 * inv * h1;
      float mx2 = fmaxf(b20, b21);
      mx2 = fmaxf(mx2, __shfl_xor(mx2, 1)); mx2 = fmaxf(mx2, __shfl_xor(mx2, 2));
      mx2 = fmaxf(mx2, __shfl_xor(mx2, 4)); mx2 = fmaxf(mx2, __shfl_xor(mx2, 8));
      const float e20 = __expf(b20 - mx2), e21 = __expf(b21 - mx2);
      float S2 = e20 + e21;
      S2 += __shfl_xor(S2, 1); S2 += __shfl_xor(S2, 2);
      S2 += __shfl_xor(S2, 4); S2 += __shfl_xor(S2, 8);
      const float inv2 = 1.0f / S2;
      c2S[op * 33 + bl] = e20 * inv2;
      c2S[(op + 16) * 33 + bl] = e21 * inv2;
    }

    // ---- phase 2c: issue global prefetch of W for nn+2 ----
    if (nn < NPER - 2) {
      const size_t nb = (size_t)(n0 + nn + 2);
      #pragma unroll
      for (int c = 0; c < 4; ++c)
        wreg[c] = *(const float4*)(W + nb * 8192 + c * 2048 + 4 * t);
    }
    __syncthreads();   // syncB: c2S ready; WA(nn+1) staged

    // ---- phase 3: weighted accumulate from retained D ----
    #pragma unroll
    for (int oo = 0; oo < 8; ++oo) {
      const int o = oq * 8 + oo;
      const float c = c2S[o * 33 + bt * 16 + dq];
      sacc[oo][0] += c * Dv[oo][0]; sacc[oo][1] += c * Dv[oo][1];
      sacc[oo][2] += c * Dv[oo][2]; sacc[oo][3] += c * Dv[oo][3];
    }
    // c2S reads here precede the next syncA; next c2S writes come after it.
  }

  // ---- epilogue: gidx-major, block-contiguous (proven clean-WRITE layout) ----
  // partial[ng][b_global][cell], cell = o*16 + d, d = q*4 + r
  float* pb = partial + (size_t)ng * 32768
            + (size_t)(bh * 32 + bt * 16 + dq) * 512 + q * 4;
  #pragma unroll
  for (int oo = 0; oo < 8; ++oo) {
    const int o = oq * 8 + oo;
    *(float4*)(pb + o * 16)
        = make_float4(sacc[oo][0], sacc[oo][1], sacc[oo][2], sacc[oo][3]);
  }
}

// ---------------- Kernel 2: reduce 256 group-partials + squash ----------------
// R10 regrid: one (b,o) pair per block (2048 blocks), 256 threads =
// 16 group-chunks x 16 d; 16 strided loads/thread; 8 blocks/CU = 32 waves/CU.
__global__ __launch_bounds__(256) void caps_reduce_kernel(
    const float* __restrict__ partial, float* __restrict__ out)
{
  const int t = threadIdx.x;
  const int pair = blockIdx.x;              // (b,o), 2048 total
  const int b = pair >> 5, o = pair & 31;
  const int d = t & 15, g16 = t >> 4;
  const float* p = partial + (size_t)b * 512 + o * 16 + d;
  float s = 0.f;
  #pragma unroll
  for (int k = 0; k < 16; ++k)
    s += p[(size_t)(g16 + k * 16) * 32768];
  __shared__ float red[16][17];
  red[g16][d] = s;
  __syncthreads();
  if (t < 16) {
    float sd = 0.f;
    #pragma unroll
    for (int g = 0; g < 16; ++g) sd += red[g][t];
    float s2 = sd * sd;
    s2 += __shfl_xor(s2, 1); s2 += __shfl_xor(s2, 2);
    s2 += __shfl_xor(s2, 4); s2 += __shfl_xor(s2, 8);   // over d (lanes 0-15)
    float scale = s2 / (1.0f + s2) / sqrtf(s2 + 1e-7f);
    out[(size_t)b * 512 + o * 16 + t] = scale * sd;
  }
}

extern "C" void kernel_launch(void* const* d_in, const int* in_sizes, int n_in,
                              void* d_out, int out_size, void* d_ws, size_t ws_size,
                              hipStream_t stream) {
  const float* x = (const float*)d_in[0];   // [64,2048,16]
  const float* W = (const float*)d_in[1];   // [1,2048,32,16,16]
  if (in_sizes[0] != 64 * 2048 * 16) { const float* tmp = x; x = W; W = tmp; }
  float* out = (float*)d_out;               // [64,32,16]

  float* partial = (float*)d_ws;            // 256*32768 f32 = 33.5 MB (gidx-major)

  caps_fused_kernel<<<512, 512, 0, stream>>>(x, W, partial);
  caps_reduce_kernel<<<2048, 256, 0, stream>>>(partial, out);
}